// Round 21
// baseline (613.852 us; speedup 1.0000x reference)
//
#include <hip/hip_runtime.h>

// ---------- types ----------
typedef __attribute__((ext_vector_type(8))) short short8;   // 8 x bf16
typedef __attribute__((ext_vector_type(4))) float f32x4;
typedef __attribute__((ext_vector_type(16))) float f32x16;

typedef __attribute__((address_space(1))) const void gas1_t;
typedef __attribute__((address_space(3))) void las3_t;
#define GLL16(g, l) __builtin_amdgcn_global_load_lds((gas1_t*)(g), (las3_t*)(l), 16, 0, 0)

__device__ inline unsigned short f2bf(float f) {
  union { float f; unsigned int u; } v; v.f = f;
  unsigned int r = v.u + 0x7FFFu + ((v.u >> 16) & 1u);
  return (unsigned short)(r >> 16);
}

__device__ inline float exp2_fast(float x) {
  float r; asm("v_exp_f32 %0, %1" : "=v"(r) : "v"(x)); return r;
}

__device__ inline void vmwait(int n) {
  if (n == 6)      asm volatile("s_waitcnt vmcnt(6)" ::: "memory");
  else             asm volatile("s_waitcnt vmcnt(0)" ::: "memory");
}

// ---------- LayerNorm (f32 in, bf16 out), one row per block ----------
__global__ __launch_bounds__(256) void ln_kernel(const float* __restrict__ x,
                                                 const float* __restrict__ w,
                                                 const float* __restrict__ bia,
                                                 unsigned short* __restrict__ out) {
  const int row = blockIdx.x;
  const int tid = threadIdx.x;
  const float* xr = x + (size_t)row * 2048;
  float4 a = *(const float4*)(xr + tid * 8);
  float4 b = *(const float4*)(xr + tid * 8 + 4);
  float s  = a.x + a.y + a.z + a.w + b.x + b.y + b.z + b.w;
  float s2 = a.x*a.x + a.y*a.y + a.z*a.z + a.w*a.w + b.x*b.x + b.y*b.y + b.z*b.z + b.w*b.w;
  #pragma unroll
  for (int off = 1; off < 64; off <<= 1) {
    s  += __shfl_xor(s, off);
    s2 += __shfl_xor(s2, off);
  }
  __shared__ float red[8];
  if ((tid & 63) == 0) { red[tid >> 6] = s; red[4 + (tid >> 6)] = s2; }
  __syncthreads();
  s  = red[0] + red[1] + red[2] + red[3];
  s2 = red[4] + red[5] + red[6] + red[7];
  const float mean = s * (1.f / 2048.f);
  const float var  = s2 * (1.f / 2048.f) - mean * mean;
  const float rstd = rsqrtf(var + 1e-5f);
  float4 wa = *(const float4*)(w + tid * 8), wb = *(const float4*)(w + tid * 8 + 4);
  float4 ba = *(const float4*)(bia + tid * 8), bb = *(const float4*)(bia + tid * 8 + 4);
  short8 o;
  o[0] = (short)f2bf((a.x - mean) * rstd * wa.x + ba.x);
  o[1] = (short)f2bf((a.y - mean) * rstd * wa.y + ba.y);
  o[2] = (short)f2bf((a.z - mean) * rstd * wa.z + ba.z);
  o[3] = (short)f2bf((a.w - mean) * rstd * wa.w + ba.w);
  o[4] = (short)f2bf((b.x - mean) * rstd * wb.x + bb.x);
  o[5] = (short)f2bf((b.y - mean) * rstd * wb.y + bb.y);
  o[6] = (short)f2bf((b.z - mean) * rstd * wb.z + bb.z);
  o[7] = (short)f2bf((b.w - mean) * rstd * wb.w + bb.w);
  *(short8*)(out + (size_t)row * 2048 + tid * 8) = o;
}

// ---------- f32 -> bf16 convert (single range) ----------
__global__ __launch_bounds__(256) void conv_kernel(const float* __restrict__ in,
                                                   unsigned short* __restrict__ out, int n) {
  size_t idx = ((size_t)blockIdx.x * 256 + threadIdx.x) * 8;
  if (idx >= (size_t)n) return;
  float4 a = *(const float4*)(in + idx);
  float4 b = *(const float4*)(in + idx + 4);
  short8 o;
  o[0] = (short)f2bf(a.x); o[1] = (short)f2bf(a.y);
  o[2] = (short)f2bf(a.z); o[3] = (short)f2bf(a.w);
  o[4] = (short)f2bf(b.x); o[5] = (short)f2bf(b.y);
  o[6] = (short)f2bf(b.z); o[7] = (short)f2bf(b.w);
  *(short8*)(out + idx) = o;
}

// ---------- 3-range f32 -> bf16 convert: wout (4194304) | w1 (524288) | w2 (524288) ----------
__global__ __launch_bounds__(256) void conv3_kernel(const float* __restrict__ wo,
                                                    const float* __restrict__ w1,
                                                    const float* __restrict__ w2,
                                                    unsigned short* __restrict__ out) {
  size_t idx = ((size_t)blockIdx.x * 256 + threadIdx.x) * 8;
  if (idx >= 5242880) return;
  const float* src;
  if (idx < 4194304)      src = wo + idx;
  else if (idx < 4718592) src = w1 + (idx - 4194304);
  else                    src = w2 + (idx - 4718592);
  float4 a = *(const float4*)(src);
  float4 b = *(const float4*)(src + 4);
  short8 o;
  o[0] = (short)f2bf(a.x); o[1] = (short)f2bf(a.y);
  o[2] = (short)f2bf(a.z); o[3] = (short)f2bf(a.w);
  o[4] = (short)f2bf(b.x); o[5] = (short)f2bf(b.y);
  o[6] = (short)f2bf(b.z); o[7] = (short)f2bf(b.w);
  *(short8*)(out + idx) = o;
}

// ---------- GEMM 128x128 (proven): used for MLP1 ----------
// MODE 1: relu + bf16 (stride N)
template <int MODE>
__global__ __launch_bounds__(256) void gemm_bt(const unsigned short* __restrict__ A,
                                               const unsigned short* __restrict__ Bw,
                                               const float* __restrict__ bias,
                                               const float* __restrict__ res,
                                               void* __restrict__ outp,
                                               void* __restrict__ outp2,
                                               int M, int N, int K) {
  __shared__ unsigned short As[128 * 64];
  __shared__ unsigned short Bs[128 * 64];
  const int tid = threadIdx.x;
  const int l = tid & 63, wv = tid >> 6;
  const int l15 = l & 15, l4 = l >> 4;
  const int wr = wv >> 1, wc = wv & 1;
  const int nx = gridDim.x;
  const int nwg = nx * gridDim.y;
  const int bidlin = blockIdx.y * nx + blockIdx.x;
  const int cpx = nwg >> 3;
  const int swz = (bidlin & 7) * cpx + (bidlin >> 3);
  const int m0 = (swz / nx) * 128, n0 = (swz % nx) * 128;

  f32x4 acc[4][4] = {};
  for (int k0 = 0; k0 < K; k0 += 64) {
    __syncthreads();
    #pragma unroll
    for (int i = 0; i < 4; ++i) {
      int e = i * 2048 + tid * 8;
      int r = e >> 6;
      int c = (e ^ ((r & 7) << 3)) & 63;  // pre-swizzled source, linear LDS dest
      GLL16(A + (size_t)(m0 + r) * K + k0 + c, As + e);
      GLL16(Bw + (size_t)(n0 + r) * K + k0 + c, Bs + e);
    }
    __syncthreads();
    #pragma unroll
    for (int kk = 0; kk < 64; kk += 32) {
      short8 af[4], bfr[4];
      #pragma unroll
      for (int m = 0; m < 4; ++m) {
        int r = wr * 64 + m * 16 + l15;
        int byt = (r * 128 + (kk + l4 * 8) * 2) ^ ((r & 7) << 4);
        af[m] = *(const short8*)((const char*)As + byt);
      }
      #pragma unroll
      for (int n = 0; n < 4; ++n) {
        int r = wc * 64 + n * 16 + l15;
        int byt = (r * 128 + (kk + l4 * 8) * 2) ^ ((r & 7) << 4);
        bfr[n] = *(const short8*)((const char*)Bs + byt);
      }
      #pragma unroll
      for (int m = 0; m < 4; ++m)
        #pragma unroll
        for (int n = 0; n < 4; ++n)
          acc[m][n] = __builtin_amdgcn_mfma_f32_16x16x32_bf16(af[m], bfr[n], acc[m][n], 0, 0, 0);
    }
  }
  #pragma unroll
  for (int m = 0; m < 4; ++m) {
    #pragma unroll
    for (int n = 0; n < 4; ++n) {
      #pragma unroll
      for (int r = 0; r < 4; ++r) {
        int row = m0 + wr * 64 + m * 16 + l4 * 4 + r;
        int col = n0 + wc * 64 + n * 16 + l15;
        float v = acc[m][n][r] + bias[col];
        if (MODE == 1) {
          ((unsigned short*)outp)[(size_t)row * N + col] = f2bf(v > 0.f ? v : 0.f);
        } else {
          ((float*)outp)[(size_t)row * N + col] = res[(size_t)row * N + col] + v;
        }
      }
    }
  }
}

// ---------- GEMM 256x256, 2-phase/tile, balanced counted lgkm ----------
// MODE 2: f32 out = res + acc + bias (stride N)
// MODE 4: merged QKV: blocks with n0<4096 -> QK bf16 store (stride 4096 into outp);
//         blocks with n0>=4096 -> operand-swapped MFMA (C transposed) and V
//         transposed store into outp2 = vT[b][h][128][2048], pad rows zeroed.
template <int MODE>
__global__ __launch_bounds__(512, 2) void gemm8(const unsigned short* __restrict__ A,
                                                const unsigned short* __restrict__ Bw,
                                                const float* __restrict__ bias,
                                                const float* __restrict__ res,
                                                const int* __restrict__ amask,
                                                void* __restrict__ outp,
                                                void* __restrict__ outp2,
                                                int M, int N, int K) {
  __shared__ char LA[2][2][16384];
  __shared__ char LB[2][2][16384];
  const int tid = threadIdx.x;              // 0..511
  const int l = tid & 63, wv = tid >> 6;    // 8 waves
  const int l15 = l & 15, l4 = l >> 4;
  const int wr = wv >> 2, wc = wv & 3;      // 2(M) x 4(N)
  const int wch = wc >> 1, wcl = wc & 1;    // B half / sub
  const int nx = gridDim.x;
  const int nwg = nx * gridDim.y;
  const int bidlin = blockIdx.y * nx + blockIdx.x;
  const int cpx = nwg >> 3;
  const int swz = (bidlin & 7) * cpx + (bidlin >> 3);
  const int m0 = (swz / nx) * 256, n0 = (swz % nx) * 256;
  const bool vblk = (MODE == 4) && (n0 >= 4096);

  const int srow = tid >> 3;                       // 0..63
  const int scol = ((tid & 7) ^ (srow & 7)) * 8;   // inverse of read swizzle

#define STG_A(x, h) { const unsigned short* bp = A + (size_t)(m0 + (h) * 128) * K + (x) * 64; \
    GLL16(bp + (size_t)srow * K + scol, &LA[(x) & 1][h][tid * 16]); \
    GLL16(bp + (size_t)(srow + 64) * K + scol, &LA[(x) & 1][h][8192 + tid * 16]); }
#define STG_B(x, h) { const unsigned short* bp = Bw + (size_t)(n0 + (h) * 128) * K + (x) * 64; \
    GLL16(bp + (size_t)srow * K + scol, &LB[(x) & 1][h][tid * 16]); \
    GLL16(bp + (size_t)(srow + 64) * K + scol, &LB[(x) & 1][h][8192 + tid * 16]); }

#define FOFF(r, kh) ((r) * 128 + (((((kh) * 4 + l4)) ^ ((r) & 7)) << 4))

  f32x4 acc[8][4] = {};
  const int NT = K >> 6;

  // prologue: T0 all + T1.{B0,B1,A0}  (issue order = drain order)
  STG_A(0, 0); STG_A(0, 1); STG_B(0, 0); STG_B(0, 1);
  STG_B(1, 0); STG_B(1, 1); STG_A(1, 0);
  vmwait(6);
  __builtin_amdgcn_s_barrier();

  // 16 MFMA for one (mh, kh); SW literal selects operand order (C transposed if 1)
#define MFMAK(mh, kh, SW) \
    __builtin_amdgcn_s_setprio(1); \
    _Pragma("unroll") for (int f = 0; f < 4; ++f) \
      _Pragma("unroll") for (int n = 0; n < 4; ++n) { \
        if (SW) \
          acc[(mh) * 4 + f][n] = __builtin_amdgcn_mfma_f32_16x16x32_bf16( \
              bfr[kh][n], af[kh][f], acc[(mh) * 4 + f][n], 0, 0, 0); \
        else \
          acc[(mh) * 4 + f][n] = __builtin_amdgcn_mfma_f32_16x16x32_bf16( \
              af[kh][f], bfr[kh][n], acc[(mh) * 4 + f][n], 0, 0, 0); \
      } \
    __builtin_amdgcn_s_setprio(0);

#define KLOOP(SW) \
  for (int t = 0; t < NT; ++t) { \
    const char* Ab = LA[t & 1][wr]; \
    const char* Bb = LB[t & 1][wch]; \
    short8 af[2][4], bfr[2][4]; \
    _Pragma("unroll") for (int f = 0; f < 4; ++f) { \
      bfr[0][f] = *(const short8*)(Bb + FOFF(wcl * 64 + f * 16 + l15, 0)); \
      af[0][f]  = *(const short8*)(Ab + FOFF(f * 16 + l15, 0)); \
    } \
    __builtin_amdgcn_sched_barrier(0); \
    _Pragma("unroll") for (int f = 0; f < 4; ++f) { \
      bfr[1][f] = *(const short8*)(Bb + FOFF(wcl * 64 + f * 16 + l15, 1)); \
      af[1][f]  = *(const short8*)(Ab + FOFF(f * 16 + l15, 1)); \
    } \
    if (t + 1 < NT) STG_A(t + 1, 1); \
    __builtin_amdgcn_s_barrier(); \
    asm volatile("s_waitcnt lgkmcnt(8)" ::: "memory"); \
    __builtin_amdgcn_sched_barrier(0); \
    MFMAK(0, 0, SW); \
    asm volatile("s_waitcnt lgkmcnt(0)" ::: "memory"); \
    __builtin_amdgcn_sched_barrier(0); \
    MFMAK(0, 1, SW); \
    __builtin_amdgcn_s_barrier(); \
    _Pragma("unroll") for (int f = 0; f < 4; ++f) \
      af[0][f] = *(const short8*)(Ab + FOFF(64 + f * 16 + l15, 0)); \
    __builtin_amdgcn_sched_barrier(0); \
    _Pragma("unroll") for (int f = 0; f < 4; ++f) \
      af[1][f] = *(const short8*)(Ab + FOFF(64 + f * 16 + l15, 1)); \
    if (t + 2 < NT) { STG_B(t + 2, 0); STG_B(t + 2, 1); STG_A(t + 2, 0); } \
    __builtin_amdgcn_s_barrier(); \
    asm volatile("s_waitcnt lgkmcnt(4)" ::: "memory"); \
    __builtin_amdgcn_sched_barrier(0); \
    MFMAK(1, 0, SW); \
    asm volatile("s_waitcnt lgkmcnt(0)" ::: "memory"); \
    __builtin_amdgcn_sched_barrier(0); \
    MFMAK(1, 1, SW); \
    vmwait(t >= NT - 2 ? 0 : 6); \
    __builtin_amdgcn_s_barrier(); \
  }

  if (MODE == 4) {
    if (vblk) { KLOOP(1) } else { KLOOP(0) }
  } else {
    KLOOP(0)
  }
#undef KLOOP
#undef MFMAK
#undef FOFF
#undef STG_A
#undef STG_B

  #pragma unroll
  for (int mf = 0; mf < 8; ++mf) {
    int tokenv = 0, amv = 1;
    if (MODE == 4) {
      tokenv = m0 + wr * 128 + mf * 16 + l15;
      if (vblk) amv = amask[tokenv];
    }
    #pragma unroll
    for (int nf = 0; nf < 4; ++nf) {
      #pragma unroll
      for (int r = 0; r < 4; ++r) {
        if (MODE == 4) {
          if (vblk) {
            // C transposed: col=token (l15), row=v-col (l4*4+r); zero padded tokens
            int col = n0 + wc * 64 + nf * 16 + l4 * 4 + r;   // 4096..6143
            float v = (amv != 0) ? (acc[mf][nf][r] + bias[col]) : 0.f;
            int vcol = col - 4096;
            int hh = vcol >> 7, d = vcol & 127;
            int bb = tokenv >> 11;
            ((unsigned short*)outp2)[((size_t)(bb * 16 + hh) * 128 + d) * 2048 +
                                     (tokenv & 2047)] = f2bf(v);
          } else {
            int col = n0 + wc * 64 + nf * 16 + l15;
            float v = acc[mf][nf][r] + bias[col];
            int row = m0 + wr * 128 + mf * 16 + l4 * 4 + r;
            ((unsigned short*)outp)[(size_t)row * 4096 + col] = f2bf(v);
          }
        } else {
          int row = m0 + wr * 128 + mf * 16 + l4 * 4 + r;
          int col = n0 + wc * 64 + nf * 16 + l15;
          float v = acc[mf][nf][r] + bias[col];
          ((float*)outp)[(size_t)row * N + col] = res[(size_t)row * N + col] + v;
        }
      }
    }
  }
}

// ---------- Flash attention: swapped QK^T + permlane32_swap P, validity-vector lsum ----------
__global__ __launch_bounds__(256) void attn_kernel(const unsigned short* __restrict__ qk,
                                                   const unsigned short* __restrict__ vT,
                                                   const int* __restrict__ amask,
                                                   unsigned short* __restrict__ ctx) {
  __shared__ unsigned short Ks[2][4096];   // [key=32][d=128], XOR (key&7)<<4 on byte
  __shared__ unsigned short Vs[2][4096];   // [d=128][key=32], XOR (d&6)<<3 on byte
  __shared__ unsigned short validbf[2048]; // bf16 1.0/0.0 per key of this batch

  // XCD-aware swizzle: each XCD gets 8 contiguous (b,h) pairs (K/V L2 locality)
  const int lin = blockIdx.y * 16 + blockIdx.x;   // grid (16,64) -> 1024 blocks
  const int swzb = (lin & 7) * 128 + (lin >> 3);
  const int qt = swzb & 15, bh = swzb >> 4;
  const int b = bh >> 4, h = bh & 15;
  const int tid = threadIdx.x;
  const int wv = tid >> 6, l = tid & 63;
  const int l31 = l & 31, hi = l >> 5;
  const int q0w = qt * 128 + wv * 32;
  const float SC2 = 0.08838834764831845f * 1.4426950408889634f; // scale * log2e
  const float L2E = 1.4426950408889634f;
  const float MF  = 10.0f;  // static max (log2 domain)

  int kinv[2], vinv[2];
  #pragma unroll
  for (int c = 0; c < 2; ++c) {
    int e = c * 2048 + tid * 8;
    int key = e >> 7, d0 = e & 127;
    kinv[c] = key * 4096 + 2048 + h * 128 + (d0 ^ ((key & 7) << 3));
    int d = e >> 5, kchunk = ((e >> 3) & 3) ^ ((d & 6) >> 1);
    vinv[c] = d * 2048 + kchunk * 8;
  }
  const unsigned short* kb0 = qk + (size_t)(b * 2048) * 4096;
  const unsigned short* vb0 = vT + (size_t)(b * 16 + h) * (128 * 2048);
  const int* mrow = amask + b * 2048;

  // fill validity table (once): 8 keys per thread
  {
    int i8 = tid * 8;
    short8 vv;
    #pragma unroll
    for (int j = 0; j < 8; ++j) vv[j] = (short)(mrow[i8 + j] ? 0x3F80 : 0);
    *(short8*)&validbf[i8] = vv;
  }

  // Q frags (B-operand): col=q=l31, k = c*16 + hi*8 + j over d
  short8 qf[8];
  {
    const unsigned short* qp = qk + (size_t)(b * 2048 + q0w + l31) * 4096 + h * 128 + hi * 8;
    #pragma unroll
    for (int c = 0; c < 8; ++c) qf[c] = *(const short8*)(qp + c * 16);
  }

  f32x16 o[4] = {};
  f32x16 ol = {};

  #pragma unroll
  for (int c = 0; c < 2; ++c) {
    GLL16(kb0 + kinv[c], &Ks[0][c * 2048 + tid * 8]);
    GLL16(vb0 + vinv[c], &Vs[0][c * 2048 + tid * 8]);
  }
  __syncthreads();

  for (int kt = 0; kt < 2048; kt += 32) {
    const int cur = (kt >> 5) & 1;
    if (kt + 32 < 2048) {
      #pragma unroll
      for (int c = 0; c < 2; ++c) {
        GLL16(kb0 + (size_t)(kt + 32) * 4096 + kinv[c], &Ks[cur ^ 1][c * 2048 + tid * 8]);
        GLL16(vb0 + (kt + 32) + vinv[c], &Vs[cur ^ 1][c * 2048 + tid * 8]);
      }
    }

    // S = K Q (swapped): C[col=q=l31][row=key=crow(i,hi)]
    f32x16 sacc = {};
    __builtin_amdgcn_s_setprio(1);
    #pragma unroll
    for (int c = 0; c < 8; ++c) {
      short8 kf = *(const short8*)((const char*)Ks[cur] +
                   ((l31 * 256 + c * 32 + hi * 16) ^ ((l31 & 7) << 4)));
      sacc = __builtin_amdgcn_mfma_f32_32x32x16_bf16(kf, qf[c], sacc, 0, 0, 0);
    }
    __builtin_amdgcn_s_setprio(0);

    // p = exp2(s*SC2 + addc - MF); causal: key kt+ci+4hi > q q0w+l31 <=> ci > Dq
    const int Dq = q0w + l31 - kt - 4 * hi;
    float p[16];
    if (kt > q0w + 31) {             // strictly future for whole tile
      #pragma unroll
      for (int i = 0; i < 16; ++i) p[i] = sacc[i] * SC2 + (L2E - MF);
    } else if (kt + 31 <= q0w) {     // fully past-or-diagonal
      #pragma unroll
      for (int i = 0; i < 16; ++i) p[i] = sacc[i] * SC2 - MF;
    } else {
      #pragma unroll
      for (int i = 0; i < 16; ++i) {
        const int ci = (i & 3) + 8 * (i >> 2);
        p[i] = sacc[i] * SC2 + ((ci > Dq) ? (L2E - MF) : -MF);
      }
    }
    #pragma unroll
    for (int i = 0; i < 16; ++i) p[i] = exp2_fast(p[i]);

    // pack key-pairs, then permlane32_swap (vdst-upper <-> vsrc-lower) -> A-frags
#define CVTPK(dst, a, bsrc) asm("v_cvt_pk_bf16_f32 %0, %1, %2" : "=v"(dst) : "v"(a), "v"(bsrc))
#define PLSWAP(fst, snd) asm("v_permlane32_swap_b32 %0, %1" : "+v"(fst), "+v"(snd))
    unsigned x, x2, y, y2, u, u2, v, v2;
    CVTPK(x,  p[0],  p[1]);  CVTPK(x2, p[2],  p[3]);
    CVTPK(y,  p[4],  p[5]);  CVTPK(y2, p[6],  p[7]);
    CVTPK(u,  p[8],  p[9]);  CVTPK(u2, p[10], p[11]);
    CVTPK(v,  p[12], p[13]); CVTPK(v2, p[14], p[15]);
    PLSWAP(x, y);  PLSWAP(x2, y2);
    PLSWAP(u, v);  PLSWAP(u2, v2);
    union { unsigned w[4]; short8 s8; } P0, P1;
    P0.w[0] = x; P0.w[1] = x2; P0.w[2] = y; P0.w[3] = y2;
    P1.w[0] = u; P1.w[1] = u2; P1.w[2] = v; P1.w[3] = v2;
    short8 pa0 = P0.s8, pa1 = P1.s8;
#undef CVTPK
#undef PLSWAP

    // validity B-frags (broadcast reads, conflict-free)
    short8 vm0 = *(const short8*)&validbf[kt + hi * 8];
    short8 vm1 = *(const short8*)&validbf[kt + 16 + hi * 8];

    __builtin_amdgcn_s_setprio(1);
    #pragma unroll
    for (int g = 0; g < 4; ++g) {
      int d = g * 32 + l31;
      int swzd = (d & 6) << 3;
      short8 vf0 = *(const short8*)((const char*)Vs[cur] + ((d * 64 + hi * 16) ^ swzd));
      o[g] = __builtin_amdgcn_mfma_f32_32x32x16_bf16(pa0, vf0, o[g], 0, 0, 0);
      short8 vf1 = *(const short8*)((const char*)Vs[cur] + ((d * 64 + 32 + hi * 16) ^ swzd));
      o[g] = __builtin_amdgcn_mfma_f32_32x32x16_bf16(pa1, vf1, o[g], 0, 0, 0);
    }
    ol = __builtin_amdgcn_mfma_f32_32x32x16_bf16(pa0, vm0, ol, 0, 0, 0);
    ol = __builtin_amdgcn_mfma_f32_32x32x16_bf16(pa1, vm1, ol, 0, 0, 0);
    __builtin_amdgcn_s_setprio(0);

    __syncthreads();
  }

  float inv[16];
  #pragma unroll
  for (int i = 0; i < 16; ++i) inv[i] = 1.0f / ol[i];
  #pragma unroll
  for (int g = 0; g < 4; ++g) {
    #pragma unroll
    for (int i = 0; i < 16; ++i) {
      int q = q0w + (i & 3) + 8 * (i >> 2) + 4 * hi;
      ctx[(size_t)(b * 2048 + q) * 2048 + h * 128 + g * 32 + l31] = f2bf(o[g][i] * inv[i]);
    }
  }
}

// ---------- launch ----------
extern "C" void kernel_launch(void* const* d_in, const int* in_sizes, int n_in,
                              void* d_out, int out_size, void* d_ws, size_t ws_size,
                              hipStream_t stream) {
  (void)in_sizes; (void)n_in; (void)out_size; (void)ws_size;
  const float* x    = (const float*)d_in[0];
  const int*   am   = (const int*)d_in[1];
  const float* ln1w = (const float*)d_in[2];
  const float* ln1b = (const float*)d_in[3];
  const float* win  = (const float*)d_in[4];
  const float* bin  = (const float*)d_in[5];
  const float* wout = (const float*)d_in[6];
  const float* bout = (const float*)d_in[7];
  const float* ln2w = (const float*)d_in[8];
  const float* ln2b = (const float*)d_in[9];
  const float* w1   = (const float*)d_in[10];
  const float* b1   = (const float*)d_in[11];
  const float* w2   = (const float*)d_in[12];
  const float* b2   = (const float*)d_in[13];
  float* out = (float*)d_out;

  // ws layout (153.2 MB):
  //  0..32M   : h (LN1 out)          -> later ctx (attn out)
  //  32..96M  : qk [8192][4096]      -> after attn: h2 (32..64M) + midb (64..68M)
  //             + wbuf2 (68..78.5M): wout_bf | w1_bf | w2_bf
  //  96..128M : vT [b][h][128][2048] (written directly by gemm8<4>, pad rows zeroed)
  //  128M+    : wbuf (win bf16, 25.2MB)
  char* ws = (char*)d_ws;
  unsigned short* hbuf  = (unsigned short*)ws;
  unsigned short* ctxb  = (unsigned short*)ws;
  unsigned short* qkb   = (unsigned short*)(ws + (size_t)32 * 1048576);
  unsigned short* h2b   = (unsigned short*)(ws + (size_t)32 * 1048576);
  unsigned short* midb  = (unsigned short*)(ws + (size_t)64 * 1048576);
  unsigned short* wbuf2 = (unsigned short*)(ws + (size_t)68 * 1048576);
  unsigned short* vTb   = (unsigned short*)(ws + (size_t)96 * 1048576);
  unsigned short* wbuf  = (unsigned short*)(ws + (size_t)128 * 1048576);

  unsigned short* woutb = wbuf2;
  unsigned short* w1b   = wbuf2 + 4194304;
  unsigned short* w2b   = wbuf2 + 4718592;

  // 1) h = LN1(x) -> bf16
  ln_kernel<<<dim3(8192), dim3(256), 0, stream>>>(x, ln1w, ln1b, hbuf);
  // 2) in_proj_w -> bf16
  conv_kernel<<<dim3(6144), dim3(256), 0, stream>>>(win, wbuf, 12582912);
  // 3) merged QKV GEMM: QK -> qkb, V -> vT (transposed, pad-zeroed)
  gemm8<4><<<dim3(24, 32), dim3(512), 0, stream>>>(hbuf, wbuf, bin, (const float*)nullptr,
                                                   am, (void*)qkb, (void*)vTb,
                                                   8192, 6144, 2048);
  // 4) attention -> ctx (overwrites h, now dead)
  attn_kernel<<<dim3(16, 64), dim3(256), 0, stream>>>(qkb, vTb, am, ctxb);
  // 5) wout/w1/w2 -> bf16 (one kernel; into dead qk region)
  conv3_kernel<<<dim3(2560), dim3(256), 0, stream>>>(wout, w1, w2, wbuf2);
  // 6) d_out = x + ctx @ Wout^T + b  (f32)
  gemm8<2><<<dim3(8, 32), dim3(512), 0, stream>>>(ctxb, woutb, bout, x,
                                                  (const int*)nullptr, (void*)out, nullptr,
                                                  8192, 2048, 2048);
  // 7) h2 = LN2(d_out) -> bf16
  ln_kernel<<<dim3(8192), dim3(256), 0, stream>>>(out, ln2w, ln2b, h2b);
  // 8) mid = relu(h2 @ W1^T + b1)  [8192, 256] bf16
  gemm_bt<1><<<dim3(2, 64), dim3(256), 0, stream>>>(h2b, w1b, b1, (const float*)nullptr,
                                                    (void*)midb, nullptr, 8192, 256, 2048);
  // 9) d_out = d_out + mid @ W2^T + b2  (f32, gemm8 K=256)
  gemm8<2><<<dim3(8, 32), dim3(512), 0, stream>>>(midb, w2b, b2, out,
                                                  (const int*)nullptr, (void*)out, nullptr,
                                                  8192, 2048, 256);
}

// Round 22
// 578.710 us; speedup vs baseline: 1.0607x; 1.0607x over previous
//
#include <hip/hip_runtime.h>

// ---------- types ----------
typedef __attribute__((ext_vector_type(8))) short short8;   // 8 x bf16
typedef __attribute__((ext_vector_type(4))) float f32x4;
typedef __attribute__((ext_vector_type(16))) float f32x16;

typedef __attribute__((address_space(1))) const void gas1_t;
typedef __attribute__((address_space(3))) void las3_t;
#define GLL16(g, l) __builtin_amdgcn_global_load_lds((gas1_t*)(g), (las3_t*)(l), 16, 0, 0)

__device__ inline unsigned short f2bf(float f) {
  union { float f; unsigned int u; } v; v.f = f;
  unsigned int r = v.u + 0x7FFFu + ((v.u >> 16) & 1u);
  return (unsigned short)(r >> 16);
}

__device__ inline float exp2_fast(float x) {
  float r; asm("v_exp_f32 %0, %1" : "=v"(r) : "v"(x)); return r;
}

__device__ inline void vmwait(int n) {
  if (n == 6)      asm volatile("s_waitcnt vmcnt(6)" ::: "memory");
  else             asm volatile("s_waitcnt vmcnt(0)" ::: "memory");
}

// ---------- LayerNorm (f32 in, bf16 out), one row per block ----------
__global__ __launch_bounds__(256) void ln_kernel(const float* __restrict__ x,
                                                 const float* __restrict__ w,
                                                 const float* __restrict__ bia,
                                                 unsigned short* __restrict__ out) {
  const int row = blockIdx.x;
  const int tid = threadIdx.x;
  const float* xr = x + (size_t)row * 2048;
  float4 a = *(const float4*)(xr + tid * 8);
  float4 b = *(const float4*)(xr + tid * 8 + 4);
  float s  = a.x + a.y + a.z + a.w + b.x + b.y + b.z + b.w;
  float s2 = a.x*a.x + a.y*a.y + a.z*a.z + a.w*a.w + b.x*b.x + b.y*b.y + b.z*b.z + b.w*b.w;
  #pragma unroll
  for (int off = 1; off < 64; off <<= 1) {
    s  += __shfl_xor(s, off);
    s2 += __shfl_xor(s2, off);
  }
  __shared__ float red[8];
  if ((tid & 63) == 0) { red[tid >> 6] = s; red[4 + (tid >> 6)] = s2; }
  __syncthreads();
  s  = red[0] + red[1] + red[2] + red[3];
  s2 = red[4] + red[5] + red[6] + red[7];
  const float mean = s * (1.f / 2048.f);
  const float var  = s2 * (1.f / 2048.f) - mean * mean;
  const float rstd = rsqrtf(var + 1e-5f);
  float4 wa = *(const float4*)(w + tid * 8), wb = *(const float4*)(w + tid * 8 + 4);
  float4 ba = *(const float4*)(bia + tid * 8), bb = *(const float4*)(bia + tid * 8 + 4);
  short8 o;
  o[0] = (short)f2bf((a.x - mean) * rstd * wa.x + ba.x);
  o[1] = (short)f2bf((a.y - mean) * rstd * wa.y + ba.y);
  o[2] = (short)f2bf((a.z - mean) * rstd * wa.z + ba.z);
  o[3] = (short)f2bf((a.w - mean) * rstd * wa.w + ba.w);
  o[4] = (short)f2bf((b.x - mean) * rstd * wb.x + bb.x);
  o[5] = (short)f2bf((b.y - mean) * rstd * wb.y + bb.y);
  o[6] = (short)f2bf((b.z - mean) * rstd * wb.z + bb.z);
  o[7] = (short)f2bf((b.w - mean) * rstd * wb.w + bb.w);
  *(short8*)(out + (size_t)row * 2048 + tid * 8) = o;
}

// ---------- f32 -> bf16 convert (single range) ----------
__global__ __launch_bounds__(256) void conv_kernel(const float* __restrict__ in,
                                                   unsigned short* __restrict__ out, int n) {
  size_t idx = ((size_t)blockIdx.x * 256 + threadIdx.x) * 8;
  if (idx >= (size_t)n) return;
  float4 a = *(const float4*)(in + idx);
  float4 b = *(const float4*)(in + idx + 4);
  short8 o;
  o[0] = (short)f2bf(a.x); o[1] = (short)f2bf(a.y);
  o[2] = (short)f2bf(a.z); o[3] = (short)f2bf(a.w);
  o[4] = (short)f2bf(b.x); o[5] = (short)f2bf(b.y);
  o[6] = (short)f2bf(b.z); o[7] = (short)f2bf(b.w);
  *(short8*)(out + idx) = o;
}

// ---------- 3-range f32 -> bf16 convert: wout (4194304) | w1 (524288) | w2 (524288) ----------
__global__ __launch_bounds__(256) void conv3_kernel(const float* __restrict__ wo,
                                                    const float* __restrict__ w1,
                                                    const float* __restrict__ w2,
                                                    unsigned short* __restrict__ out) {
  size_t idx = ((size_t)blockIdx.x * 256 + threadIdx.x) * 8;
  if (idx >= 5242880) return;
  const float* src;
  if (idx < 4194304)      src = wo + idx;
  else if (idx < 4718592) src = w1 + (idx - 4194304);
  else                    src = w2 + (idx - 4718592);
  float4 a = *(const float4*)(src);
  float4 b = *(const float4*)(src + 4);
  short8 o;
  o[0] = (short)f2bf(a.x); o[1] = (short)f2bf(a.y);
  o[2] = (short)f2bf(a.z); o[3] = (short)f2bf(a.w);
  o[4] = (short)f2bf(b.x); o[5] = (short)f2bf(b.y);
  o[6] = (short)f2bf(b.z); o[7] = (short)f2bf(b.w);
  *(short8*)(out + idx) = o;
}

// ---------- GEMM 128x128 (proven): used for MLP1 ----------
// MODE 1: relu + bf16 (stride N)
template <int MODE>
__global__ __launch_bounds__(256) void gemm_bt(const unsigned short* __restrict__ A,
                                               const unsigned short* __restrict__ Bw,
                                               const float* __restrict__ bias,
                                               const float* __restrict__ res,
                                               void* __restrict__ outp,
                                               void* __restrict__ outp2,
                                               int M, int N, int K) {
  __shared__ unsigned short As[128 * 64];
  __shared__ unsigned short Bs[128 * 64];
  const int tid = threadIdx.x;
  const int l = tid & 63, wv = tid >> 6;
  const int l15 = l & 15, l4 = l >> 4;
  const int wr = wv >> 1, wc = wv & 1;
  const int nx = gridDim.x;
  const int nwg = nx * gridDim.y;
  const int bidlin = blockIdx.y * nx + blockIdx.x;
  const int cpx = nwg >> 3;
  const int swz = (bidlin & 7) * cpx + (bidlin >> 3);
  const int m0 = (swz / nx) * 128, n0 = (swz % nx) * 128;

  f32x4 acc[4][4] = {};
  for (int k0 = 0; k0 < K; k0 += 64) {
    __syncthreads();
    #pragma unroll
    for (int i = 0; i < 4; ++i) {
      int e = i * 2048 + tid * 8;
      int r = e >> 6;
      int c = (e ^ ((r & 7) << 3)) & 63;  // pre-swizzled source, linear LDS dest
      GLL16(A + (size_t)(m0 + r) * K + k0 + c, As + e);
      GLL16(Bw + (size_t)(n0 + r) * K + k0 + c, Bs + e);
    }
    __syncthreads();
    #pragma unroll
    for (int kk = 0; kk < 64; kk += 32) {
      short8 af[4], bfr[4];
      #pragma unroll
      for (int m = 0; m < 4; ++m) {
        int r = wr * 64 + m * 16 + l15;
        int byt = (r * 128 + (kk + l4 * 8) * 2) ^ ((r & 7) << 4);
        af[m] = *(const short8*)((const char*)As + byt);
      }
      #pragma unroll
      for (int n = 0; n < 4; ++n) {
        int r = wc * 64 + n * 16 + l15;
        int byt = (r * 128 + (kk + l4 * 8) * 2) ^ ((r & 7) << 4);
        bfr[n] = *(const short8*)((const char*)Bs + byt);
      }
      #pragma unroll
      for (int m = 0; m < 4; ++m)
        #pragma unroll
        for (int n = 0; n < 4; ++n)
          acc[m][n] = __builtin_amdgcn_mfma_f32_16x16x32_bf16(af[m], bfr[n], acc[m][n], 0, 0, 0);
    }
  }
  #pragma unroll
  for (int m = 0; m < 4; ++m) {
    #pragma unroll
    for (int n = 0; n < 4; ++n) {
      #pragma unroll
      for (int r = 0; r < 4; ++r) {
        int row = m0 + wr * 64 + m * 16 + l4 * 4 + r;
        int col = n0 + wc * 64 + n * 16 + l15;
        float v = acc[m][n][r] + bias[col];
        if (MODE == 1) {
          ((unsigned short*)outp)[(size_t)row * N + col] = f2bf(v > 0.f ? v : 0.f);
        } else {
          ((float*)outp)[(size_t)row * N + col] = res[(size_t)row * N + col] + v;
        }
      }
    }
  }
}

// ---------- GEMM 256x256, 2-phase/tile, balanced counted lgkm (proven) ----------
// MODE 0: bf16 out stride 4096 (QK)
// MODE 2: f32 out = res + acc + bias (stride N)
// MODE 3: V -> vT transposed store (swapped MFMA operands, C transposed);
//         padded tokens' V rows stored as ZERO (amask).
template <int MODE>
__global__ __launch_bounds__(512, 2) void gemm8(const unsigned short* __restrict__ A,
                                                const unsigned short* __restrict__ Bw,
                                                const float* __restrict__ bias,
                                                const float* __restrict__ res,
                                                const int* __restrict__ amask,
                                                void* __restrict__ outp,
                                                int M, int N, int K) {
  __shared__ char LA[2][2][16384];
  __shared__ char LB[2][2][16384];
  const int tid = threadIdx.x;              // 0..511
  const int l = tid & 63, wv = tid >> 6;    // 8 waves
  const int l15 = l & 15, l4 = l >> 4;
  const int wr = wv >> 2, wc = wv & 3;      // 2(M) x 4(N)
  const int wch = wc >> 1, wcl = wc & 1;    // B half / sub
  const int nx = gridDim.x;
  const int nwg = nx * gridDim.y;
  const int bidlin = blockIdx.y * nx + blockIdx.x;
  const int cpx = nwg >> 3;
  const int swz = (bidlin & 7) * cpx + (bidlin >> 3);
  const int m0 = (swz / nx) * 256, n0 = (swz % nx) * 256;

  const int srow = tid >> 3;                       // 0..63
  const int scol = ((tid & 7) ^ (srow & 7)) * 8;   // inverse of read swizzle

#define STG_A(x, h) { const unsigned short* bp = A + (size_t)(m0 + (h) * 128) * K + (x) * 64; \
    GLL16(bp + (size_t)srow * K + scol, &LA[(x) & 1][h][tid * 16]); \
    GLL16(bp + (size_t)(srow + 64) * K + scol, &LA[(x) & 1][h][8192 + tid * 16]); }
#define STG_B(x, h) { const unsigned short* bp = Bw + (size_t)(n0 + (h) * 128) * K + (x) * 64; \
    GLL16(bp + (size_t)srow * K + scol, &LB[(x) & 1][h][tid * 16]); \
    GLL16(bp + (size_t)(srow + 64) * K + scol, &LB[(x) & 1][h][8192 + tid * 16]); }

#define FOFF(r, kh) ((r) * 128 + (((((kh) * 4 + l4)) ^ ((r) & 7)) << 4))

  f32x4 acc[8][4] = {};
  const int NT = K >> 6;

  // prologue: T0 all + T1.{B0,B1,A0}  (issue order = drain order)
  STG_A(0, 0); STG_A(0, 1); STG_B(0, 0); STG_B(0, 1);
  STG_B(1, 0); STG_B(1, 1); STG_A(1, 0);
  vmwait(6);
  __builtin_amdgcn_s_barrier();

  // 16 MFMA for one (mh, kh); MODE 3 swaps operands (C transposed)
#define MFMAK(mh, kh) \
    __builtin_amdgcn_s_setprio(1); \
    _Pragma("unroll") for (int f = 0; f < 4; ++f) \
      _Pragma("unroll") for (int n = 0; n < 4; ++n) { \
        if (MODE == 3) \
          acc[(mh) * 4 + f][n] = __builtin_amdgcn_mfma_f32_16x16x32_bf16( \
              bfr[kh][n], af[kh][f], acc[(mh) * 4 + f][n], 0, 0, 0); \
        else \
          acc[(mh) * 4 + f][n] = __builtin_amdgcn_mfma_f32_16x16x32_bf16( \
              af[kh][f], bfr[kh][n], acc[(mh) * 4 + f][n], 0, 0, 0); \
      } \
    __builtin_amdgcn_s_setprio(0);

  for (int t = 0; t < NT; ++t) {
    const char* Ab = LA[t & 1][wr];
    const char* Bb = LB[t & 1][wch];
    short8 af[2][4], bfr[2][4];
    // ---- ph1: ordered reads {B-k0,A0-k0} | {B-k1,A0-k1}; stage (t+1).A1
    #pragma unroll
    for (int f = 0; f < 4; ++f) {
      bfr[0][f] = *(const short8*)(Bb + FOFF(wcl * 64 + f * 16 + l15, 0));
      af[0][f]  = *(const short8*)(Ab + FOFF(f * 16 + l15, 0));
    }
    __builtin_amdgcn_sched_barrier(0);
    #pragma unroll
    for (int f = 0; f < 4; ++f) {
      bfr[1][f] = *(const short8*)(Bb + FOFF(wcl * 64 + f * 16 + l15, 1));
      af[1][f]  = *(const short8*)(Ab + FOFF(f * 16 + l15, 1));
    }
    if (t + 1 < NT) STG_A(t + 1, 1);
    __builtin_amdgcn_s_barrier();
    asm volatile("s_waitcnt lgkmcnt(8)" ::: "memory");
    __builtin_amdgcn_sched_barrier(0);
    MFMAK(0, 0);
    asm volatile("s_waitcnt lgkmcnt(0)" ::: "memory");
    __builtin_amdgcn_sched_barrier(0);
    MFMAK(0, 1);
    __builtin_amdgcn_s_barrier();
    // ---- ph2: ordered reads {A1-k0} | {A1-k1}; stage (t+2).{B0,B1,A0}
    #pragma unroll
    for (int f = 0; f < 4; ++f)
      af[0][f] = *(const short8*)(Ab + FOFF(64 + f * 16 + l15, 0));
    __builtin_amdgcn_sched_barrier(0);
    #pragma unroll
    for (int f = 0; f < 4; ++f)
      af[1][f] = *(const short8*)(Ab + FOFF(64 + f * 16 + l15, 1));
    if (t + 2 < NT) { STG_B(t + 2, 0); STG_B(t + 2, 1); STG_A(t + 2, 0); }
    __builtin_amdgcn_s_barrier();
    asm volatile("s_waitcnt lgkmcnt(4)" ::: "memory");
    __builtin_amdgcn_sched_barrier(0);
    MFMAK(1, 0);
    asm volatile("s_waitcnt lgkmcnt(0)" ::: "memory");
    __builtin_amdgcn_sched_barrier(0);
    MFMAK(1, 1);
    vmwait(t >= NT - 2 ? 0 : 6);
    __builtin_amdgcn_s_barrier();
  }
#undef MFMAK
#undef FOFF
#undef STG_A
#undef STG_B

  #pragma unroll
  for (int mf = 0; mf < 8; ++mf) {
    int tokenv = 0, amv = 1;
    if (MODE == 3) {
      tokenv = m0 + wr * 128 + mf * 16 + l15;
      amv = amask[tokenv];
    }
    #pragma unroll
    for (int nf = 0; nf < 4; ++nf) {
      #pragma unroll
      for (int r = 0; r < 4; ++r) {
        if (MODE == 3) {
          // C transposed: col=token (l15), row=v-col (l4*4+r); zero padded tokens
          int vcol = n0 + wc * 64 + nf * 16 + l4 * 4 + r;
          float v = (amv != 0) ? (acc[mf][nf][r] + bias[vcol]) : 0.f;
          int hh = vcol >> 7, d = vcol & 127;
          int bb = tokenv >> 11;
          ((unsigned short*)outp)[((size_t)(bb * 16 + hh) * 128 + d) * 2048 +
                                  (tokenv & 2047)] = f2bf(v);
        } else {
          int row = m0 + wr * 128 + mf * 16 + l4 * 4 + r;
          int col = n0 + wc * 64 + nf * 16 + l15;
          float v = acc[mf][nf][r] + bias[col];
          if (MODE == 0) {
            ((unsigned short*)outp)[(size_t)row * 4096 + col] = f2bf(v);
          } else {
            ((float*)outp)[(size_t)row * N + col] = res[(size_t)row * N + col] + v;
          }
        }
      }
    }
  }
}

// ---------- Flash attention: swapped QK^T + permlane32_swap P, validity-vector lsum ----------
__global__ __launch_bounds__(256) void attn_kernel(const unsigned short* __restrict__ qk,
                                                   const unsigned short* __restrict__ vT,
                                                   const int* __restrict__ amask,
                                                   unsigned short* __restrict__ ctx) {
  __shared__ unsigned short Ks[2][4096];   // [key=32][d=128], XOR (key&7)<<4 on byte
  __shared__ unsigned short Vs[2][4096];   // [d=128][key=32], XOR (d&6)<<3 on byte
  __shared__ unsigned short validbf[2048]; // bf16 1.0/0.0 per key of this batch

  // XCD-aware swizzle: each XCD gets 8 contiguous (b,h) pairs (K/V L2 locality)
  const int lin = blockIdx.y * 16 + blockIdx.x;   // grid (16,64) -> 1024 blocks
  const int swzb = (lin & 7) * 128 + (lin >> 3);
  const int qt = swzb & 15, bh = swzb >> 4;
  const int b = bh >> 4, h = bh & 15;
  const int tid = threadIdx.x;
  const int wv = tid >> 6, l = tid & 63;
  const int l31 = l & 31, hi = l >> 5;
  const int q0w = qt * 128 + wv * 32;
  const float SC2 = 0.08838834764831845f * 1.4426950408889634f; // scale * log2e
  const float L2E = 1.4426950408889634f;
  const float MF  = 10.0f;  // static max (log2 domain)

  int kinv[2], vinv[2];
  #pragma unroll
  for (int c = 0; c < 2; ++c) {
    int e = c * 2048 + tid * 8;
    int key = e >> 7, d0 = e & 127;
    kinv[c] = key * 4096 + 2048 + h * 128 + (d0 ^ ((key & 7) << 3));
    int d = e >> 5, kchunk = ((e >> 3) & 3) ^ ((d & 6) >> 1);
    vinv[c] = d * 2048 + kchunk * 8;
  }
  const unsigned short* kb0 = qk + (size_t)(b * 2048) * 4096;
  const unsigned short* vb0 = vT + (size_t)(b * 16 + h) * (128 * 2048);
  const int* mrow = amask + b * 2048;

  // fill validity table (once): 8 keys per thread
  {
    int i8 = tid * 8;
    short8 vv;
    #pragma unroll
    for (int j = 0; j < 8; ++j) vv[j] = (short)(mrow[i8 + j] ? 0x3F80 : 0);
    *(short8*)&validbf[i8] = vv;
  }

  // Q frags (B-operand): col=q=l31, k = c*16 + hi*8 + j over d
  short8 qf[8];
  {
    const unsigned short* qp = qk + (size_t)(b * 2048 + q0w + l31) * 4096 + h * 128 + hi * 8;
    #pragma unroll
    for (int c = 0; c < 8; ++c) qf[c] = *(const short8*)(qp + c * 16);
  }

  f32x16 o[4] = {};
  f32x16 ol = {};

  #pragma unroll
  for (int c = 0; c < 2; ++c) {
    GLL16(kb0 + kinv[c], &Ks[0][c * 2048 + tid * 8]);
    GLL16(vb0 + vinv[c], &Vs[0][c * 2048 + tid * 8]);
  }
  __syncthreads();

  for (int kt = 0; kt < 2048; kt += 32) {
    const int cur = (kt >> 5) & 1;
    if (kt + 32 < 2048) {
      #pragma unroll
      for (int c = 0; c < 2; ++c) {
        GLL16(kb0 + (size_t)(kt + 32) * 4096 + kinv[c], &Ks[cur ^ 1][c * 2048 + tid * 8]);
        GLL16(vb0 + (kt + 32) + vinv[c], &Vs[cur ^ 1][c * 2048 + tid * 8]);
      }
    }

    // S = K Q (swapped): C[col=q=l31][row=key=crow(i,hi)]
    f32x16 sacc = {};
    __builtin_amdgcn_s_setprio(1);
    #pragma unroll
    for (int c = 0; c < 8; ++c) {
      short8 kf = *(const short8*)((const char*)Ks[cur] +
                   ((l31 * 256 + c * 32 + hi * 16) ^ ((l31 & 7) << 4)));
      sacc = __builtin_amdgcn_mfma_f32_32x32x16_bf16(kf, qf[c], sacc, 0, 0, 0);
    }
    __builtin_amdgcn_s_setprio(0);

    // p = exp2(s*SC2 + addc - MF); causal: key kt+ci+4hi > q q0w+l31 <=> ci > Dq
    const int Dq = q0w + l31 - kt - 4 * hi;
    float p[16];
    if (kt > q0w + 31) {             // strictly future for whole tile
      #pragma unroll
      for (int i = 0; i < 16; ++i) p[i] = sacc[i] * SC2 + (L2E - MF);
    } else if (kt + 31 <= q0w) {     // fully past-or-diagonal
      #pragma unroll
      for (int i = 0; i < 16; ++i) p[i] = sacc[i] * SC2 - MF;
    } else {
      #pragma unroll
      for (int i = 0; i < 16; ++i) {
        const int ci = (i & 3) + 8 * (i >> 2);
        p[i] = sacc[i] * SC2 + ((ci > Dq) ? (L2E - MF) : -MF);
      }
    }
    #pragma unroll
    for (int i = 0; i < 16; ++i) p[i] = exp2_fast(p[i]);

    // pack key-pairs, then permlane32_swap (vdst-upper <-> vsrc-lower) -> A-frags
#define CVTPK(dst, a, bsrc) asm("v_cvt_pk_bf16_f32 %0, %1, %2" : "=v"(dst) : "v"(a), "v"(bsrc))
#define PLSWAP(fst, snd) asm("v_permlane32_swap_b32 %0, %1" : "+v"(fst), "+v"(snd))
    unsigned x, x2, y, y2, u, u2, v, v2;
    CVTPK(x,  p[0],  p[1]);  CVTPK(x2, p[2],  p[3]);
    CVTPK(y,  p[4],  p[5]);  CVTPK(y2, p[6],  p[7]);
    CVTPK(u,  p[8],  p[9]);  CVTPK(u2, p[10], p[11]);
    CVTPK(v,  p[12], p[13]); CVTPK(v2, p[14], p[15]);
    PLSWAP(x, y);  PLSWAP(x2, y2);
    PLSWAP(u, v);  PLSWAP(u2, v2);
    union { unsigned w[4]; short8 s8; } P0, P1;
    P0.w[0] = x; P0.w[1] = x2; P0.w[2] = y; P0.w[3] = y2;
    P1.w[0] = u; P1.w[1] = u2; P1.w[2] = v; P1.w[3] = v2;
    short8 pa0 = P0.s8, pa1 = P1.s8;
#undef CVTPK
#undef PLSWAP

    // validity B-frags (broadcast reads, conflict-free)
    short8 vm0 = *(const short8*)&validbf[kt + hi * 8];
    short8 vm1 = *(const short8*)&validbf[kt + 16 + hi * 8];

    __builtin_amdgcn_s_setprio(1);
    #pragma unroll
    for (int g = 0; g < 4; ++g) {
      int d = g * 32 + l31;
      int swzd = (d & 6) << 3;
      short8 vf0 = *(const short8*)((const char*)Vs[cur] + ((d * 64 + hi * 16) ^ swzd));
      o[g] = __builtin_amdgcn_mfma_f32_32x32x16_bf16(pa0, vf0, o[g], 0, 0, 0);
      short8 vf1 = *(const short8*)((const char*)Vs[cur] + ((d * 64 + 32 + hi * 16) ^ swzd));
      o[g] = __builtin_amdgcn_mfma_f32_32x32x16_bf16(pa1, vf1, o[g], 0, 0, 0);
    }
    ol = __builtin_amdgcn_mfma_f32_32x32x16_bf16(pa0, vm0, ol, 0, 0, 0);
    ol = __builtin_amdgcn_mfma_f32_32x32x16_bf16(pa1, vm1, ol, 0, 0, 0);
    __builtin_amdgcn_s_setprio(0);

    __syncthreads();
  }

  float inv[16];
  #pragma unroll
  for (int i = 0; i < 16; ++i) inv[i] = 1.0f / ol[i];
  #pragma unroll
  for (int g = 0; g < 4; ++g) {
    #pragma unroll
    for (int i = 0; i < 16; ++i) {
      int q = q0w + (i & 3) + 8 * (i >> 2) + 4 * hi;
      ctx[(size_t)(b * 2048 + q) * 2048 + h * 128 + g * 32 + l31] = f2bf(o[g][i] * inv[i]);
    }
  }
}

// ---------- launch ----------
extern "C" void kernel_launch(void* const* d_in, const int* in_sizes, int n_in,
                              void* d_out, int out_size, void* d_ws, size_t ws_size,
                              hipStream_t stream) {
  (void)in_sizes; (void)n_in; (void)out_size; (void)ws_size;
  const float* x    = (const float*)d_in[0];
  const int*   am   = (const int*)d_in[1];
  const float* ln1w = (const float*)d_in[2];
  const float* ln1b = (const float*)d_in[3];
  const float* win  = (const float*)d_in[4];
  const float* bin  = (const float*)d_in[5];
  const float* wout = (const float*)d_in[6];
  const float* bout = (const float*)d_in[7];
  const float* ln2w = (const float*)d_in[8];
  const float* ln2b = (const float*)d_in[9];
  const float* w1   = (const float*)d_in[10];
  const float* b1   = (const float*)d_in[11];
  const float* w2   = (const float*)d_in[12];
  const float* b2   = (const float*)d_in[13];
  float* out = (float*)d_out;

  // ws layout (153.2 MB):
  //  0..32M   : h (LN1 out)          -> later ctx (attn out)
  //  32..96M  : qk [8192][4096]      -> after attn: h2 (32..64M) + midb (64..68M)
  //             + wbuf2 (68..78.5M): wout_bf | w1_bf | w2_bf
  //  96..128M : vT [b][h][128][2048] (written directly by gemm8<3>, pad rows zeroed)
  //  128M+    : wbuf (win bf16, 25.2MB)
  char* ws = (char*)d_ws;
  unsigned short* hbuf  = (unsigned short*)ws;
  unsigned short* ctxb  = (unsigned short*)ws;
  unsigned short* qkb   = (unsigned short*)(ws + (size_t)32 * 1048576);
  unsigned short* h2b   = (unsigned short*)(ws + (size_t)32 * 1048576);
  unsigned short* midb  = (unsigned short*)(ws + (size_t)64 * 1048576);
  unsigned short* wbuf2 = (unsigned short*)(ws + (size_t)68 * 1048576);
  unsigned short* vTb   = (unsigned short*)(ws + (size_t)96 * 1048576);
  unsigned short* wbuf  = (unsigned short*)(ws + (size_t)128 * 1048576);

  unsigned short* woutb = wbuf2;
  unsigned short* w1b   = wbuf2 + 4194304;
  unsigned short* w2b   = wbuf2 + 4718592;

  // 1) h = LN1(x) -> bf16
  ln_kernel<<<dim3(8192), dim3(256), 0, stream>>>(x, ln1w, ln1b, hbuf);
  // 2) in_proj_w -> bf16
  conv_kernel<<<dim3(6144), dim3(256), 0, stream>>>(win, wbuf, 12582912);
  // 3a) QK GEMM: cols 0..4095 -> qkb
  gemm8<0><<<dim3(16, 32), dim3(512), 0, stream>>>(hbuf, wbuf, bin, (const float*)nullptr,
                                                   (const int*)nullptr, (void*)qkb,
                                                   8192, 4096, 2048);
  // 3b) V GEMM (transposed store, pad rows zeroed): cols 4096..6143 -> vT
  gemm8<3><<<dim3(8, 32), dim3(512), 0, stream>>>(hbuf, wbuf + (size_t)4096 * 2048,
                                                  bin + 4096, (const float*)nullptr,
                                                  am, (void*)vTb, 8192, 2048, 2048);
  // 4) attention -> ctx (overwrites h, now dead)
  attn_kernel<<<dim3(16, 64), dim3(256), 0, stream>>>(qkb, vTb, am, ctxb);
  // 5) wout/w1/w2 -> bf16 (one kernel; into dead qk region)
  conv3_kernel<<<dim3(2560), dim3(256), 0, stream>>>(wout, w1, w2, wbuf2);
  // 6) d_out = x + ctx @ Wout^T + b  (f32)
  gemm8<2><<<dim3(8, 32), dim3(512), 0, stream>>>(ctxb, woutb, bout, x,
                                                  (const int*)nullptr, (void*)out,
                                                  8192, 2048, 2048);
  // 7) h2 = LN2(d_out) -> bf16
  ln_kernel<<<dim3(8192), dim3(256), 0, stream>>>(out, ln2w, ln2b, h2b);
  // 8) mid = relu(h2 @ W1^T + b1)  [8192, 256] bf16
  gemm_bt<1><<<dim3(2, 64), dim3(256), 0, stream>>>(h2b, w1b, b1, (const float*)nullptr,
                                                    (void*)midb, nullptr, 8192, 256, 2048);
  // 9) d_out = d_out + mid @ W2^T + b2  (f32, gemm8 K=256)
  gemm8<2><<<dim3(8, 32), dim3(512), 0, stream>>>(midb, w2b, b2, out,
                                                  (const int*)nullptr, (void*)out,
                                                  8192, 2048, 256);
}

// Round 23
// 569.277 us; speedup vs baseline: 1.0783x; 1.0166x over previous
//
#include <hip/hip_runtime.h>

// ---------- types ----------
typedef __attribute__((ext_vector_type(8))) short short8;   // 8 x bf16
typedef __attribute__((ext_vector_type(4))) float f32x4;
typedef __attribute__((ext_vector_type(16))) float f32x16;

typedef __attribute__((address_space(1))) const void gas1_t;
typedef __attribute__((address_space(3))) void las3_t;
#define GLL16(g, l) __builtin_amdgcn_global_load_lds((gas1_t*)(g), (las3_t*)(l), 16, 0, 0)

__device__ inline unsigned short f2bf(float f) {
  union { float f; unsigned int u; } v; v.f = f;
  unsigned int r = v.u + 0x7FFFu + ((v.u >> 16) & 1u);
  return (unsigned short)(r >> 16);
}

__device__ inline float exp2_fast(float x) {
  float r; asm("v_exp_f32 %0, %1" : "=v"(r) : "v"(x)); return r;
}

__device__ inline void vmwait(int n) {
  if (n == 6)      asm volatile("s_waitcnt vmcnt(6)" ::: "memory");
  else             asm volatile("s_waitcnt vmcnt(0)" ::: "memory");
}

// ---------- LayerNorm (f32 in, bf16 out), one row per block ----------
__global__ __launch_bounds__(256) void ln_kernel(const float* __restrict__ x,
                                                 const float* __restrict__ w,
                                                 const float* __restrict__ bia,
                                                 unsigned short* __restrict__ out) {
  const int row = blockIdx.x;
  const int tid = threadIdx.x;
  const float* xr = x + (size_t)row * 2048;
  float4 a = *(const float4*)(xr + tid * 8);
  float4 b = *(const float4*)(xr + tid * 8 + 4);
  float s  = a.x + a.y + a.z + a.w + b.x + b.y + b.z + b.w;
  float s2 = a.x*a.x + a.y*a.y + a.z*a.z + a.w*a.w + b.x*b.x + b.y*b.y + b.z*b.z + b.w*b.w;
  #pragma unroll
  for (int off = 1; off < 64; off <<= 1) {
    s  += __shfl_xor(s, off);
    s2 += __shfl_xor(s2, off);
  }
  __shared__ float red[8];
  if ((tid & 63) == 0) { red[tid >> 6] = s; red[4 + (tid >> 6)] = s2; }
  __syncthreads();
  s  = red[0] + red[1] + red[2] + red[3];
  s2 = red[4] + red[5] + red[6] + red[7];
  const float mean = s * (1.f / 2048.f);
  const float var  = s2 * (1.f / 2048.f) - mean * mean;
  const float rstd = rsqrtf(var + 1e-5f);
  float4 wa = *(const float4*)(w + tid * 8), wb = *(const float4*)(w + tid * 8 + 4);
  float4 ba = *(const float4*)(bia + tid * 8), bb = *(const float4*)(bia + tid * 8 + 4);
  short8 o;
  o[0] = (short)f2bf((a.x - mean) * rstd * wa.x + ba.x);
  o[1] = (short)f2bf((a.y - mean) * rstd * wa.y + ba.y);
  o[2] = (short)f2bf((a.z - mean) * rstd * wa.z + ba.z);
  o[3] = (short)f2bf((a.w - mean) * rstd * wa.w + ba.w);
  o[4] = (short)f2bf((b.x - mean) * rstd * wb.x + bb.x);
  o[5] = (short)f2bf((b.y - mean) * rstd * wb.y + bb.y);
  o[6] = (short)f2bf((b.z - mean) * rstd * wb.z + bb.z);
  o[7] = (short)f2bf((b.w - mean) * rstd * wb.w + bb.w);
  *(short8*)(out + (size_t)row * 2048 + tid * 8) = o;
}

// ---------- f32 -> bf16 convert (single range) ----------
__global__ __launch_bounds__(256) void conv_kernel(const float* __restrict__ in,
                                                   unsigned short* __restrict__ out, int n) {
  size_t idx = ((size_t)blockIdx.x * 256 + threadIdx.x) * 8;
  if (idx >= (size_t)n) return;
  float4 a = *(const float4*)(in + idx);
  float4 b = *(const float4*)(in + idx + 4);
  short8 o;
  o[0] = (short)f2bf(a.x); o[1] = (short)f2bf(a.y);
  o[2] = (short)f2bf(a.z); o[3] = (short)f2bf(a.w);
  o[4] = (short)f2bf(b.x); o[5] = (short)f2bf(b.y);
  o[6] = (short)f2bf(b.z); o[7] = (short)f2bf(b.w);
  *(short8*)(out + idx) = o;
}

// ---------- 3-range f32 -> bf16 convert: wout (4194304) | w1 (524288) | w2 (524288) ----------
__global__ __launch_bounds__(256) void conv3_kernel(const float* __restrict__ wo,
                                                    const float* __restrict__ w1,
                                                    const float* __restrict__ w2,
                                                    unsigned short* __restrict__ out) {
  size_t idx = ((size_t)blockIdx.x * 256 + threadIdx.x) * 8;
  if (idx >= 5242880) return;
  const float* src;
  if (idx < 4194304)      src = wo + idx;
  else if (idx < 4718592) src = w1 + (idx - 4194304);
  else                    src = w2 + (idx - 4718592);
  float4 a = *(const float4*)(src);
  float4 b = *(const float4*)(src + 4);
  short8 o;
  o[0] = (short)f2bf(a.x); o[1] = (short)f2bf(a.y);
  o[2] = (short)f2bf(a.z); o[3] = (short)f2bf(a.w);
  o[4] = (short)f2bf(b.x); o[5] = (short)f2bf(b.y);
  o[6] = (short)f2bf(b.z); o[7] = (short)f2bf(b.w);
  *(short8*)(out + idx) = o;
}

// ---------- GEMM 128x64 tile (MLP1): relu + bf16 out, stride N ----------
// BM=128, BN=64, BK=64; 4 waves = 2(M) x 2(N); per wave 64x32 = acc[4][2].
// Grid (N/64, M/128) = (4, 64) = 256 blocks -> full GPU for N=256.
__global__ __launch_bounds__(256) void gemm_mlp1(const unsigned short* __restrict__ A,
                                                 const unsigned short* __restrict__ Bw,
                                                 const float* __restrict__ bias,
                                                 unsigned short* __restrict__ outp,
                                                 int M, int N, int K) {
  __shared__ unsigned short As[128 * 64];
  __shared__ unsigned short Bs[64 * 64];
  const int tid = threadIdx.x;
  const int l = tid & 63, wv = tid >> 6;
  const int l15 = l & 15, l4 = l >> 4;
  const int wr = wv >> 1, wc = wv & 1;
  const int nx = gridDim.x;
  const int nwg = nx * gridDim.y;
  const int bidlin = blockIdx.y * nx + blockIdx.x;
  const int cpx = nwg >> 3;
  const int swz = (bidlin & 7) * cpx + (bidlin >> 3);
  const int m0 = (swz / nx) * 128, n0 = (swz % nx) * 64;

  f32x4 acc[4][2] = {};
  for (int k0 = 0; k0 < K; k0 += 64) {
    __syncthreads();
    #pragma unroll
    for (int i = 0; i < 4; ++i) {
      int e = i * 2048 + tid * 8;
      int r = e >> 6;
      int c = (e ^ ((r & 7) << 3)) & 63;  // pre-swizzled source, linear LDS dest
      GLL16(A + (size_t)(m0 + r) * K + k0 + c, As + e);
    }
    #pragma unroll
    for (int i = 0; i < 2; ++i) {
      int e = i * 2048 + tid * 8;
      int r = e >> 6;
      int c = (e ^ ((r & 7) << 3)) & 63;
      GLL16(Bw + (size_t)(n0 + r) * K + k0 + c, Bs + e);
    }
    __syncthreads();
    #pragma unroll
    for (int kk = 0; kk < 64; kk += 32) {
      short8 af[4], bfr[2];
      #pragma unroll
      for (int m = 0; m < 4; ++m) {
        int r = wr * 64 + m * 16 + l15;
        int byt = (r * 128 + (kk + l4 * 8) * 2) ^ ((r & 7) << 4);
        af[m] = *(const short8*)((const char*)As + byt);
      }
      #pragma unroll
      for (int n = 0; n < 2; ++n) {
        int r = wc * 32 + n * 16 + l15;
        int byt = (r * 128 + (kk + l4 * 8) * 2) ^ ((r & 7) << 4);
        bfr[n] = *(const short8*)((const char*)Bs + byt);
      }
      #pragma unroll
      for (int m = 0; m < 4; ++m)
        #pragma unroll
        for (int n = 0; n < 2; ++n)
          acc[m][n] = __builtin_amdgcn_mfma_f32_16x16x32_bf16(af[m], bfr[n], acc[m][n], 0, 0, 0);
    }
  }
  #pragma unroll
  for (int m = 0; m < 4; ++m) {
    #pragma unroll
    for (int n = 0; n < 2; ++n) {
      #pragma unroll
      for (int r = 0; r < 4; ++r) {
        int row = m0 + wr * 64 + m * 16 + l4 * 4 + r;
        int col = n0 + wc * 32 + n * 16 + l15;
        float v = acc[m][n][r] + bias[col];
        outp[(size_t)row * N + col] = f2bf(v > 0.f ? v : 0.f);
      }
    }
  }
}

// ---------- GEMM 256x256, 2-phase/tile, balanced counted lgkm (proven) ----------
// MODE 0: bf16 out stride 4096 (QK)
// MODE 2: f32 out = res + acc + bias (stride N)
// MODE 3: V -> vT transposed store (swapped MFMA operands, C transposed);
//         padded tokens' V rows stored as ZERO (amask).
template <int MODE>
__global__ __launch_bounds__(512, 2) void gemm8(const unsigned short* __restrict__ A,
                                                const unsigned short* __restrict__ Bw,
                                                const float* __restrict__ bias,
                                                const float* __restrict__ res,
                                                const int* __restrict__ amask,
                                                void* __restrict__ outp,
                                                int M, int N, int K) {
  __shared__ char LA[2][2][16384];
  __shared__ char LB[2][2][16384];
  const int tid = threadIdx.x;              // 0..511
  const int l = tid & 63, wv = tid >> 6;    // 8 waves
  const int l15 = l & 15, l4 = l >> 4;
  const int wr = wv >> 2, wc = wv & 3;      // 2(M) x 4(N)
  const int wch = wc >> 1, wcl = wc & 1;    // B half / sub
  const int nx = gridDim.x;
  const int nwg = nx * gridDim.y;
  const int bidlin = blockIdx.y * nx + blockIdx.x;
  const int cpx = nwg >> 3;
  const int swz = (bidlin & 7) * cpx + (bidlin >> 3);
  const int m0 = (swz / nx) * 256, n0 = (swz % nx) * 256;

  const int srow = tid >> 3;                       // 0..63
  const int scol = ((tid & 7) ^ (srow & 7)) * 8;   // inverse of read swizzle

#define STG_A(x, h) { const unsigned short* bp = A + (size_t)(m0 + (h) * 128) * K + (x) * 64; \
    GLL16(bp + (size_t)srow * K + scol, &LA[(x) & 1][h][tid * 16]); \
    GLL16(bp + (size_t)(srow + 64) * K + scol, &LA[(x) & 1][h][8192 + tid * 16]); }
#define STG_B(x, h) { const unsigned short* bp = Bw + (size_t)(n0 + (h) * 128) * K + (x) * 64; \
    GLL16(bp + (size_t)srow * K + scol, &LB[(x) & 1][h][tid * 16]); \
    GLL16(bp + (size_t)(srow + 64) * K + scol, &LB[(x) & 1][h][8192 + tid * 16]); }

#define FOFF(r, kh) ((r) * 128 + (((((kh) * 4 + l4)) ^ ((r) & 7)) << 4))

  f32x4 acc[8][4] = {};
  const int NT = K >> 6;

  // prologue: T0 all + T1.{B0,B1,A0}  (issue order = drain order)
  STG_A(0, 0); STG_A(0, 1); STG_B(0, 0); STG_B(0, 1);
  STG_B(1, 0); STG_B(1, 1); STG_A(1, 0);
  vmwait(6);
  __builtin_amdgcn_s_barrier();

  // 16 MFMA for one (mh, kh); MODE 3 swaps operands (C transposed)
#define MFMAK(mh, kh) \
    __builtin_amdgcn_s_setprio(1); \
    _Pragma("unroll") for (int f = 0; f < 4; ++f) \
      _Pragma("unroll") for (int n = 0; n < 4; ++n) { \
        if (MODE == 3) \
          acc[(mh) * 4 + f][n] = __builtin_amdgcn_mfma_f32_16x16x32_bf16( \
              bfr[kh][n], af[kh][f], acc[(mh) * 4 + f][n], 0, 0, 0); \
        else \
          acc[(mh) * 4 + f][n] = __builtin_amdgcn_mfma_f32_16x16x32_bf16( \
              af[kh][f], bfr[kh][n], acc[(mh) * 4 + f][n], 0, 0, 0); \
      } \
    __builtin_amdgcn_s_setprio(0);

  for (int t = 0; t < NT; ++t) {
    const char* Ab = LA[t & 1][wr];
    const char* Bb = LB[t & 1][wch];
    short8 af[2][4], bfr[2][4];
    // ---- ph1: ordered reads {B-k0,A0-k0} | {B-k1,A0-k1}; stage (t+1).A1
    #pragma unroll
    for (int f = 0; f < 4; ++f) {
      bfr[0][f] = *(const short8*)(Bb + FOFF(wcl * 64 + f * 16 + l15, 0));
      af[0][f]  = *(const short8*)(Ab + FOFF(f * 16 + l15, 0));
    }
    __builtin_amdgcn_sched_barrier(0);
    #pragma unroll
    for (int f = 0; f < 4; ++f) {
      bfr[1][f] = *(const short8*)(Bb + FOFF(wcl * 64 + f * 16 + l15, 1));
      af[1][f]  = *(const short8*)(Ab + FOFF(f * 16 + l15, 1));
    }
    if (t + 1 < NT) STG_A(t + 1, 1);
    __builtin_amdgcn_s_barrier();
    asm volatile("s_waitcnt lgkmcnt(8)" ::: "memory");
    __builtin_amdgcn_sched_barrier(0);
    MFMAK(0, 0);
    asm volatile("s_waitcnt lgkmcnt(0)" ::: "memory");
    __builtin_amdgcn_sched_barrier(0);
    MFMAK(0, 1);
    __builtin_amdgcn_s_barrier();
    // ---- ph2: ordered reads {A1-k0} | {A1-k1}; stage (t+2).{B0,B1,A0}
    #pragma unroll
    for (int f = 0; f < 4; ++f)
      af[0][f] = *(const short8*)(Ab + FOFF(64 + f * 16 + l15, 0));
    __builtin_amdgcn_sched_barrier(0);
    #pragma unroll
    for (int f = 0; f < 4; ++f)
      af[1][f] = *(const short8*)(Ab + FOFF(64 + f * 16 + l15, 1));
    if (t + 2 < NT) { STG_B(t + 2, 0); STG_B(t + 2, 1); STG_A(t + 2, 0); }
    __builtin_amdgcn_s_barrier();
    asm volatile("s_waitcnt lgkmcnt(4)" ::: "memory");
    __builtin_amdgcn_sched_barrier(0);
    MFMAK(1, 0);
    asm volatile("s_waitcnt lgkmcnt(0)" ::: "memory");
    __builtin_amdgcn_sched_barrier(0);
    MFMAK(1, 1);
    vmwait(t >= NT - 2 ? 0 : 6);
    __builtin_amdgcn_s_barrier();
  }
#undef MFMAK
#undef FOFF
#undef STG_A
#undef STG_B

  #pragma unroll
  for (int mf = 0; mf < 8; ++mf) {
    int tokenv = 0, amv = 1;
    if (MODE == 3) {
      tokenv = m0 + wr * 128 + mf * 16 + l15;
      amv = amask[tokenv];
    }
    #pragma unroll
    for (int nf = 0; nf < 4; ++nf) {
      #pragma unroll
      for (int r = 0; r < 4; ++r) {
        if (MODE == 3) {
          // C transposed: col=token (l15), row=v-col (l4*4+r); zero padded tokens
          int vcol = n0 + wc * 64 + nf * 16 + l4 * 4 + r;
          float v = (amv != 0) ? (acc[mf][nf][r] + bias[vcol]) : 0.f;
          int hh = vcol >> 7, d = vcol & 127;
          int bb = tokenv >> 11;
          ((unsigned short*)outp)[((size_t)(bb * 16 + hh) * 128 + d) * 2048 +
                                  (tokenv & 2047)] = f2bf(v);
        } else {
          int row = m0 + wr * 128 + mf * 16 + l4 * 4 + r;
          int col = n0 + wc * 64 + nf * 16 + l15;
          float v = acc[mf][nf][r] + bias[col];
          if (MODE == 0) {
            ((unsigned short*)outp)[(size_t)row * 4096 + col] = f2bf(v);
          } else {
            ((float*)outp)[(size_t)row * N + col] = res[(size_t)row * N + col] + v;
          }
        }
      }
    }
  }
}

// ---------- Flash attention: swapped QK^T + permlane32_swap P, validity-vector lsum ----------
__global__ __launch_bounds__(256) void attn_kernel(const unsigned short* __restrict__ qk,
                                                   const unsigned short* __restrict__ vT,
                                                   const int* __restrict__ amask,
                                                   unsigned short* __restrict__ ctx) {
  __shared__ unsigned short Ks[2][4096];   // [key=32][d=128], XOR (key&7)<<4 on byte
  __shared__ unsigned short Vs[2][4096];   // [d=128][key=32], XOR (d&6)<<3 on byte
  __shared__ unsigned short validbf[2048]; // bf16 1.0/0.0 per key of this batch

  // XCD-aware swizzle: each XCD gets 8 contiguous (b,h) pairs (K/V L2 locality)
  const int lin = blockIdx.y * 16 + blockIdx.x;   // grid (16,64) -> 1024 blocks
  const int swzb = (lin & 7) * 128 + (lin >> 3);
  const int qt = swzb & 15, bh = swzb >> 4;
  const int b = bh >> 4, h = bh & 15;
  const int tid = threadIdx.x;
  const int wv = tid >> 6, l = tid & 63;
  const int l31 = l & 31, hi = l >> 5;
  const int q0w = qt * 128 + wv * 32;
  const float SC2 = 0.08838834764831845f * 1.4426950408889634f; // scale * log2e
  const float L2E = 1.4426950408889634f;
  const float MF  = 10.0f;  // static max (log2 domain)

  int kinv[2], vinv[2];
  #pragma unroll
  for (int c = 0; c < 2; ++c) {
    int e = c * 2048 + tid * 8;
    int key = e >> 7, d0 = e & 127;
    kinv[c] = key * 4096 + 2048 + h * 128 + (d0 ^ ((key & 7) << 3));
    int d = e >> 5, kchunk = ((e >> 3) & 3) ^ ((d & 6) >> 1);
    vinv[c] = d * 2048 + kchunk * 8;
  }
  const unsigned short* kb0 = qk + (size_t)(b * 2048) * 4096;
  const unsigned short* vb0 = vT + (size_t)(b * 16 + h) * (128 * 2048);
  const int* mrow = amask + b * 2048;

  // fill validity table (once): 8 keys per thread
  {
    int i8 = tid * 8;
    short8 vv;
    #pragma unroll
    for (int j = 0; j < 8; ++j) vv[j] = (short)(mrow[i8 + j] ? 0x3F80 : 0);
    *(short8*)&validbf[i8] = vv;
  }

  // Q frags (B-operand): col=q=l31, k = c*16 + hi*8 + j over d
  short8 qf[8];
  {
    const unsigned short* qp = qk + (size_t)(b * 2048 + q0w + l31) * 4096 + h * 128 + hi * 8;
    #pragma unroll
    for (int c = 0; c < 8; ++c) qf[c] = *(const short8*)(qp + c * 16);
  }

  f32x16 o[4] = {};
  f32x16 ol = {};

  #pragma unroll
  for (int c = 0; c < 2; ++c) {
    GLL16(kb0 + kinv[c], &Ks[0][c * 2048 + tid * 8]);
    GLL16(vb0 + vinv[c], &Vs[0][c * 2048 + tid * 8]);
  }
  __syncthreads();

  for (int kt = 0; kt < 2048; kt += 32) {
    const int cur = (kt >> 5) & 1;
    if (kt + 32 < 2048) {
      #pragma unroll
      for (int c = 0; c < 2; ++c) {
        GLL16(kb0 + (size_t)(kt + 32) * 4096 + kinv[c], &Ks[cur ^ 1][c * 2048 + tid * 8]);
        GLL16(vb0 + (kt + 32) + vinv[c], &Vs[cur ^ 1][c * 2048 + tid * 8]);
      }
    }

    // S = K Q (swapped): C[col=q=l31][row=key=crow(i,hi)]
    f32x16 sacc = {};
    __builtin_amdgcn_s_setprio(1);
    #pragma unroll
    for (int c = 0; c < 8; ++c) {
      short8 kf = *(const short8*)((const char*)Ks[cur] +
                   ((l31 * 256 + c * 32 + hi * 16) ^ ((l31 & 7) << 4)));
      sacc = __builtin_amdgcn_mfma_f32_32x32x16_bf16(kf, qf[c], sacc, 0, 0, 0);
    }
    __builtin_amdgcn_s_setprio(0);

    // p = exp2(s*SC2 + addc - MF); causal: key kt+ci+4hi > q q0w+l31 <=> ci > Dq
    const int Dq = q0w + l31 - kt - 4 * hi;
    float p[16];
    if (kt > q0w + 31) {             // strictly future for whole tile
      #pragma unroll
      for (int i = 0; i < 16; ++i) p[i] = sacc[i] * SC2 + (L2E - MF);
    } else if (kt + 31 <= q0w) {     // fully past-or-diagonal
      #pragma unroll
      for (int i = 0; i < 16; ++i) p[i] = sacc[i] * SC2 - MF;
    } else {
      #pragma unroll
      for (int i = 0; i < 16; ++i) {
        const int ci = (i & 3) + 8 * (i >> 2);
        p[i] = sacc[i] * SC2 + ((ci > Dq) ? (L2E - MF) : -MF);
      }
    }
    #pragma unroll
    for (int i = 0; i < 16; ++i) p[i] = exp2_fast(p[i]);

    // pack key-pairs, then permlane32_swap (vdst-upper <-> vsrc-lower) -> A-frags
#define CVTPK(dst, a, bsrc) asm("v_cvt_pk_bf16_f32 %0, %1, %2" : "=v"(dst) : "v"(a), "v"(bsrc))
#define PLSWAP(fst, snd) asm("v_permlane32_swap_b32 %0, %1" : "+v"(fst), "+v"(snd))
    unsigned x, x2, y, y2, u, u2, v, v2;
    CVTPK(x,  p[0],  p[1]);  CVTPK(x2, p[2],  p[3]);
    CVTPK(y,  p[4],  p[5]);  CVTPK(y2, p[6],  p[7]);
    CVTPK(u,  p[8],  p[9]);  CVTPK(u2, p[10], p[11]);
    CVTPK(v,  p[12], p[13]); CVTPK(v2, p[14], p[15]);
    PLSWAP(x, y);  PLSWAP(x2, y2);
    PLSWAP(u, v);  PLSWAP(u2, v2);
    union { unsigned w[4]; short8 s8; } P0, P1;
    P0.w[0] = x; P0.w[1] = x2; P0.w[2] = y; P0.w[3] = y2;
    P1.w[0] = u; P1.w[1] = u2; P1.w[2] = v; P1.w[3] = v2;
    short8 pa0 = P0.s8, pa1 = P1.s8;
#undef CVTPK
#undef PLSWAP

    // validity B-frags (broadcast reads, conflict-free)
    short8 vm0 = *(const short8*)&validbf[kt + hi * 8];
    short8 vm1 = *(const short8*)&validbf[kt + 16 + hi * 8];

    __builtin_amdgcn_s_setprio(1);
    #pragma unroll
    for (int g = 0; g < 4; ++g) {
      int d = g * 32 + l31;
      int swzd = (d & 6) << 3;
      short8 vf0 = *(const short8*)((const char*)Vs[cur] + ((d * 64 + hi * 16) ^ swzd));
      o[g] = __builtin_amdgcn_mfma_f32_32x32x16_bf16(pa0, vf0, o[g], 0, 0, 0);
      short8 vf1 = *(const short8*)((const char*)Vs[cur] + ((d * 64 + 32 + hi * 16) ^ swzd));
      o[g] = __builtin_amdgcn_mfma_f32_32x32x16_bf16(pa1, vf1, o[g], 0, 0, 0);
    }
    ol = __builtin_amdgcn_mfma_f32_32x32x16_bf16(pa0, vm0, ol, 0, 0, 0);
    ol = __builtin_amdgcn_mfma_f32_32x32x16_bf16(pa1, vm1, ol, 0, 0, 0);
    __builtin_amdgcn_s_setprio(0);

    __syncthreads();
  }

  float inv[16];
  #pragma unroll
  for (int i = 0; i < 16; ++i) inv[i] = 1.0f / ol[i];
  #pragma unroll
  for (int g = 0; g < 4; ++g) {
    #pragma unroll
    for (int i = 0; i < 16; ++i) {
      int q = q0w + (i & 3) + 8 * (i >> 2) + 4 * hi;
      ctx[(size_t)(b * 2048 + q) * 2048 + h * 128 + g * 32 + l31] = f2bf(o[g][i] * inv[i]);
    }
  }
}

// ---------- launch ----------
extern "C" void kernel_launch(void* const* d_in, const int* in_sizes, int n_in,
                              void* d_out, int out_size, void* d_ws, size_t ws_size,
                              hipStream_t stream) {
  (void)in_sizes; (void)n_in; (void)out_size; (void)ws_size;
  const float* x    = (const float*)d_in[0];
  const int*   am   = (const int*)d_in[1];
  const float* ln1w = (const float*)d_in[2];
  const float* ln1b = (const float*)d_in[3];
  const float* win  = (const float*)d_in[4];
  const float* bin  = (const float*)d_in[5];
  const float* wout = (const float*)d_in[6];
  const float* bout = (const float*)d_in[7];
  const float* ln2w = (const float*)d_in[8];
  const float* ln2b = (const float*)d_in[9];
  const float* w1   = (const float*)d_in[10];
  const float* b1   = (const float*)d_in[11];
  const float* w2   = (const float*)d_in[12];
  const float* b2   = (const float*)d_in[13];
  float* out = (float*)d_out;

  // ws layout (153.2 MB):
  //  0..32M   : h (LN1 out)          -> later ctx (attn out)
  //  32..96M  : qk [8192][4096]      -> after attn: h2 (32..64M) + midb (64..68M)
  //             + wbuf2 (68..78.5M): wout_bf | w1_bf | w2_bf
  //  96..128M : vT [b][h][128][2048] (written directly by gemm8<3>, pad rows zeroed)
  //  128M+    : wbuf (win bf16, 25.2MB)
  char* ws = (char*)d_ws;
  unsigned short* hbuf  = (unsigned short*)ws;
  unsigned short* ctxb  = (unsigned short*)ws;
  unsigned short* qkb   = (unsigned short*)(ws + (size_t)32 * 1048576);
  unsigned short* h2b   = (unsigned short*)(ws + (size_t)32 * 1048576);
  unsigned short* midb  = (unsigned short*)(ws + (size_t)64 * 1048576);
  unsigned short* wbuf2 = (unsigned short*)(ws + (size_t)68 * 1048576);
  unsigned short* vTb   = (unsigned short*)(ws + (size_t)96 * 1048576);
  unsigned short* wbuf  = (unsigned short*)(ws + (size_t)128 * 1048576);

  unsigned short* woutb = wbuf2;
  unsigned short* w1b   = wbuf2 + 4194304;
  unsigned short* w2b   = wbuf2 + 4718592;

  // 1) h = LN1(x) -> bf16
  ln_kernel<<<dim3(8192), dim3(256), 0, stream>>>(x, ln1w, ln1b, hbuf);
  // 2) in_proj_w -> bf16
  conv_kernel<<<dim3(6144), dim3(256), 0, stream>>>(win, wbuf, 12582912);
  // 3a) QK GEMM: cols 0..4095 -> qkb
  gemm8<0><<<dim3(16, 32), dim3(512), 0, stream>>>(hbuf, wbuf, bin, (const float*)nullptr,
                                                   (const int*)nullptr, (void*)qkb,
                                                   8192, 4096, 2048);
  // 3b) V GEMM (transposed store, pad rows zeroed): cols 4096..6143 -> vT
  gemm8<3><<<dim3(8, 32), dim3(512), 0, stream>>>(hbuf, wbuf + (size_t)4096 * 2048,
                                                  bin + 4096, (const float*)nullptr,
                                                  am, (void*)vTb, 8192, 2048, 2048);
  // 4) attention -> ctx (overwrites h, now dead)
  attn_kernel<<<dim3(16, 64), dim3(256), 0, stream>>>(qkb, vTb, am, ctxb);
  // 5) wout/w1/w2 -> bf16 (one kernel; into dead qk region)
  conv3_kernel<<<dim3(2560), dim3(256), 0, stream>>>(wout, w1, w2, wbuf2);
  // 6) d_out = x + ctx @ Wout^T + b  (f32)
  gemm8<2><<<dim3(8, 32), dim3(512), 0, stream>>>(ctxb, woutb, bout, x,
                                                  (const int*)nullptr, (void*)out,
                                                  8192, 2048, 2048);
  // 7) h2 = LN2(d_out) -> bf16
  ln_kernel<<<dim3(8192), dim3(256), 0, stream>>>(out, ln2w, ln2b, h2b);
  // 8) mid = relu(h2 @ W1^T + b1)  [8192, 256] bf16  (128x64 tiles, full GPU)
  gemm_mlp1<<<dim3(4, 64), dim3(256), 0, stream>>>(h2b, w1b, b1, midb, 8192, 256, 2048);
  // 9) d_out = d_out + mid @ W2^T + b2  (f32, gemm8 K=256)
  gemm8<2><<<dim3(8, 32), dim3(512), 0, stream>>>(midb, w2b, b2, out,
                                                  (const int*)nullptr, (void*)out,
                                                  8192, 2048, 256);
}